// Round 8
// baseline (114.931 us; speedup 1.0000x reference)
//
#include <hip/hip_runtime.h>
#include <math.h>

#define B_    2
#define C_    64
#define N_    20000
#define K_    16
#define COUT_ 64
#define TNC   64
#define NBC   ((N_ + TNC - 1) / TNC)   // 313
#define TN    16
#define NB    (N_ / TN)                // 1250 (exact)

typedef unsigned int   u32;
typedef unsigned short u16;
typedef __attribute__((ext_vector_type(8))) short bf16x8;   // 8 bf16 = 4 VGPR
typedef __attribute__((ext_vector_type(4))) float f32x4;

typedef const __attribute__((address_space(1))) void* gas1_t;
typedef __attribute__((address_space(3)))       void* las3_t;
#define GL2LDS(g, l) __builtin_amdgcn_global_load_lds((gas1_t)(g), (las3_t)(l), 16, 0, 0)

static __device__ __forceinline__ u16 f2bf(float f) {
    union { float f; u32 u; } v; v.f = f;
    u32 r = (v.u + 0x7FFFu + ((v.u >> 16) & 1u)) >> 16;  // RNE
    return (u16)r;
}
static __device__ __forceinline__ float uasf(u32 u) {
    union { u32 u; float f; } v; v.u = u; return v.f;
}

// ---------------------------------------------------------------------------
// precast (unchanged, proven): transpose+cast x -> xb [b][n][64] bf16 (128 B
// rows); last block packs W into MFMA B-fragments:
//   f = ot*4 + {0,1}: (W1-W2) cols {0..31, 32..63}
//   f = ot*4 + {2,3}:  W2     cols {0..31, 32..63}
// so feat x W^T = x_i (W1-W2)^T + x_j W2^T (no per-edge subtraction).
// ---------------------------------------------------------------------------
__global__ __launch_bounds__(256)
void precast(const float* __restrict__ x, const float* __restrict__ W,
             u16* __restrict__ xb, u16* __restrict__ wfrag) {
    const int bi = blockIdx.x;
    const int t  = threadIdx.x;

    if (bi == B_ * NBC) {               // ---- W-fragment packer (1 block) ----
        const int l  = t & 63;
        const int ot = t >> 6;
        const int o  = ot * 16 + (l & 15);
        const int cb = (l >> 4) << 3;   // 8-ch chunk within a 32-col slice
        #pragma unroll
        for (int h = 0; h < 2; ++h) {   // col half: channels h*32 + cb .. +8
            u32 p1[4], p2[4];
            #pragma unroll
            for (int jj = 0; jj < 4; ++jj) {
                int c0 = h * 32 + cb + 2 * jj, c1 = c0 + 1;
                float w1a = W[o * 128 + c0],      w1b = W[o * 128 + c1];
                float w2a = W[o * 128 + 64 + c0], w2b = W[o * 128 + 64 + c1];
                p1[jj] = (u32)f2bf(w1a - w2a) | ((u32)f2bf(w1b - w2b) << 16);
                p2[jj] = (u32)f2bf(w2a)       | ((u32)f2bf(w2b)       << 16);
            }
            *(uint4*)&wfrag[(size_t)((ot * 4 + h)     * 64 + l) * 8] =
                make_uint4(p1[0], p1[1], p1[2], p1[3]);
            *(uint4*)&wfrag[(size_t)((ot * 4 + 2 + h) * 64 + l) * 8] =
                make_uint4(p2[0], p2[1], p2[2], p2[3]);
        }
        return;
    }

    __shared__ float tile[64][68];      // [c][n_local], padded
    const int b  = bi / NBC;
    const int n0 = (bi % NBC) * TNC;
    const float* xbase = x + (size_t)b * C_ * N_;
    #pragma unroll
    for (int r = 0; r < 4; ++r) {
        int flat = r * 256 + t;
        int c = flat >> 4, ng = (flat & 15) * 4;
        int n = n0 + ng;
        float4 v;
        if (n + 3 < N_) {
            v = *(const float4*)&xbase[c * N_ + n];
        } else {
            v.x = (n     < N_) ? xbase[c * N_ + n    ] : 0.0f;
            v.y = (n + 1 < N_) ? xbase[c * N_ + n + 1] : 0.0f;
            v.z = (n + 2 < N_) ? xbase[c * N_ + n + 2] : 0.0f;
            v.w = (n + 3 < N_) ? xbase[c * N_ + n + 3] : 0.0f;
        }
        *(float4*)&tile[c][ng] = v;
    }
    __syncthreads();

    const int n = t >> 2, q = t & 3;    // node row, 16-channel quarter
    if (n0 + n < N_) {
        u32 p[8];
        #pragma unroll
        for (int jj = 0; jj < 8; ++jj) {
            float v0 = tile[q * 16 + 2 * jj][n];
            float v1 = tile[q * 16 + 2 * jj + 1][n];
            p[jj] = (u32)f2bf(v0) | ((u32)f2bf(v1) << 16);
        }
        u16* dst = xb + ((size_t)(b * N_ + n0 + n)) * 64 + q * 16;
        *(uint4*)dst       = make_uint4(p[0], p[1], p[2], p[3]);
        *(uint4*)(dst + 8) = make_uint4(p[4], p[5], p[6], p[7]);
    }
}

// ---------------------------------------------------------------------------
// fused (round-8): gather via ASYNC DMA (global_load_lds) — the one memory
// path not yet tested against the 3.5 TB/s scattered wall.
//  - Per wave per node: 4 global_load_lds with PER-LANE scattered global
//    src (lane l: row of edge l&15, 16 B chunk l>>4); LDS dest is linear
//    (base + lane*16), which IS fragment order -> ds_read_b128 at lane*16.
//  - Double-buffered per wave (4 KB x 2); issue node n+1 BEFORE waiting
//    vmcnt(4) for node n; wave in-order issue makes buffer reuse WAW-safe.
//  - W fragments AND bias staged in LDS so the counted-vmcnt region
//    contains ONLY our DMA instructions (no compiler vmem interference).
// ---------------------------------------------------------------------------
__global__ __launch_bounds__(256)
void fused(const int* __restrict__ ei, const float* __restrict__ pos,
           const u16* __restrict__ xb, const u16* __restrict__ wfrag,
           const float* __restrict__ bias, float* __restrict__ out) {
    __shared__ u16   feat[4][2][4][512];   // 32 KB [wave][buf][frag][1 KB]
    __shared__ u16   wlds[16 * 64 * 8];    // 16 KB W fragments
    __shared__ uint2 esl[256];             // (i0 | i1<<16, s) per edge
    __shared__ float bsl[64];              // bias (LDS: keep vmcnt clean)
    __shared__ float otile[16][66];        // [n_local][o], padded

    const int bi   = blockIdx.x;
    const int b    = bi / NB;
    const int n0   = (bi % NB) * TN;
    const int t    = threadIdx.x;
    const int lane = t & 63;
    const int w    = t >> 6;
    const int g    = lane >> 4;            // k-slice group 0..3
    const int col  = lane & 15;

    // ---- Phase A: edge prep + W->LDS + bias->LDS ----
    {
        const int idx = n0 * K_ + t;
        int i0 = ei[(size_t)b * N_ * K_ + idx];          // neighbor (x_j)
        int i1 = ei[((size_t)B_ + b) * N_ * K_ + idx];   // center   (x_i)
        const float* pb = pos + (size_t)b * 3 * N_;
        float dx = pb[i0]          - pb[i1];
        float dy = pb[N_ + i0]     - pb[N_ + i1];
        float dz = pb[2 * N_ + i0] - pb[2 * N_ + i1];
        float dis = sqrtf(dx * dx + dy * dy + dz * dz);
        float s = 2.0f / (1.0f + __expf(dis));           // 2*sigmoid(-dis)
        esl[t] = make_uint2((u32)i0 | ((u32)i1 << 16), __float_as_uint(s));
        #pragma unroll
        for (int r = 0; r < 4; ++r) {
            int e = r * 256 + t;
            ((uint4*)wlds)[e] = ((const uint4*)wfrag)[e];
        }
        if (t < 64) bsl[t] = bias[t];
    }
    __syncthreads();   // drains ALL compiler vmem: vmcnt == 0 entering loop

    const u16* xbase = xb + (size_t)b * N_ * 64;

    // issue node nt's 4 fragments into buf bf (per-lane scattered src)
    auto issue = [&](int nt, int bf) {
        uint2 ee = esl[nt * 16 + col];
        const u16* ri = xbase + ((size_t)(ee.x >> 16) << 6) + g * 8;     // x_i
        const u16* rj = xbase + ((size_t)(ee.x & 0xFFFFu) << 6) + g * 8; // x_j
        GL2LDS(ri,      &feat[w][bf][0][0]);   // xi ch 0:32
        GL2LDS(ri + 32, &feat[w][bf][1][0]);   // xi ch 32:64
        GL2LDS(rj,      &feat[w][bf][2][0]);   // xj ch 0:32
        GL2LDS(rj + 32, &feat[w][bf][3][0]);   // xj ch 32:64
    };

#define WF(F) (*(const bf16x8*)&wlds[(size_t)((F) * 64 + lane) * 8])

    const float bo0 = bsl[col], bo1 = bsl[16 + col],
                bo2 = bsl[32 + col], bo3 = bsl[48 + col];

    issue(w, 0);                        // prologue: node it=0 -> buf 0
    #pragma unroll
    for (int it = 0; it < 4; ++it) {
        const int nt = it * 4 + w;      // this wave's node
        const int bf = it & 1;
        if (it < 3) issue((it + 1) * 4 + w, bf ^ 1);   // prefetch next
        if (it < 3) { asm volatile("s_waitcnt vmcnt(4)" ::: "memory"); }
        else        { asm volatile("s_waitcnt vmcnt(0)" ::: "memory"); }
        __builtin_amdgcn_sched_barrier(0);

        bf16x8 f0 = *(const bf16x8*)&feat[w][bf][0][lane * 8];
        bf16x8 f1 = *(const bf16x8*)&feat[w][bf][1][lane * 8];
        bf16x8 f2 = *(const bf16x8*)&feat[w][bf][2][lane * 8];
        bf16x8 f3 = *(const bf16x8*)&feat[w][bf][3][lane * 8];

        f32x4 ac0 = {0,0,0,0}, ac1 = ac0, ac2 = ac0, ac3 = ac0;
        ac0 = __builtin_amdgcn_mfma_f32_16x16x32_bf16(f0, WF(0),  ac0, 0,0,0);
        ac0 = __builtin_amdgcn_mfma_f32_16x16x32_bf16(f1, WF(1),  ac0, 0,0,0);
        ac0 = __builtin_amdgcn_mfma_f32_16x16x32_bf16(f2, WF(2),  ac0, 0,0,0);
        ac0 = __builtin_amdgcn_mfma_f32_16x16x32_bf16(f3, WF(3),  ac0, 0,0,0);
        ac1 = __builtin_amdgcn_mfma_f32_16x16x32_bf16(f0, WF(4),  ac1, 0,0,0);
        ac1 = __builtin_amdgcn_mfma_f32_16x16x32_bf16(f1, WF(5),  ac1, 0,0,0);
        ac1 = __builtin_amdgcn_mfma_f32_16x16x32_bf16(f2, WF(6),  ac1, 0,0,0);
        ac1 = __builtin_amdgcn_mfma_f32_16x16x32_bf16(f3, WF(7),  ac1, 0,0,0);
        ac2 = __builtin_amdgcn_mfma_f32_16x16x32_bf16(f0, WF(8),  ac2, 0,0,0);
        ac2 = __builtin_amdgcn_mfma_f32_16x16x32_bf16(f1, WF(9),  ac2, 0,0,0);
        ac2 = __builtin_amdgcn_mfma_f32_16x16x32_bf16(f2, WF(10), ac2, 0,0,0);
        ac2 = __builtin_amdgcn_mfma_f32_16x16x32_bf16(f3, WF(11), ac2, 0,0,0);
        ac3 = __builtin_amdgcn_mfma_f32_16x16x32_bf16(f0, WF(12), ac3, 0,0,0);
        ac3 = __builtin_amdgcn_mfma_f32_16x16x32_bf16(f1, WF(13), ac3, 0,0,0);
        ac3 = __builtin_amdgcn_mfma_f32_16x16x32_bf16(f2, WF(14), ac3, 0,0,0);
        ac3 = __builtin_amdgcn_mfma_f32_16x16x32_bf16(f3, WF(15), ac3, 0,0,0);

        float m0 = 0.f, m1 = 0.f, m2 = 0.f, m3 = 0.f;   // relu*s >= 0
        #pragma unroll
        for (int r4 = 0; r4 < 4; ++r4) {
            float sv = uasf(esl[nt * 16 + g * 4 + r4].y);
            m0 = fmaxf(m0, fmaxf(ac0[r4] + bo0, 0.f) * sv);
            m1 = fmaxf(m1, fmaxf(ac1[r4] + bo1, 0.f) * sv);
            m2 = fmaxf(m2, fmaxf(ac2[r4] + bo2, 0.f) * sv);
            m3 = fmaxf(m3, fmaxf(ac3[r4] + bo3, 0.f) * sv);
        }
        m0 = fmaxf(m0, __shfl_xor(m0, 16)); m0 = fmaxf(m0, __shfl_xor(m0, 32));
        m1 = fmaxf(m1, __shfl_xor(m1, 16)); m1 = fmaxf(m1, __shfl_xor(m1, 32));
        m2 = fmaxf(m2, __shfl_xor(m2, 16)); m2 = fmaxf(m2, __shfl_xor(m2, 32));
        m3 = fmaxf(m3, __shfl_xor(m3, 16)); m3 = fmaxf(m3, __shfl_xor(m3, 32));
        if (lane < 16) {
            otile[nt][col]      = m0;
            otile[nt][16 + col] = m1;
            otile[nt][32 + col] = m2;
            otile[nt][48 + col] = m3;
        }
    }
#undef WF
    __syncthreads();

    // ---- coalesced writeback: 64 o x 16 n, nontemporal ----
    #pragma unroll
    for (int r = 0; r < 4; ++r) {
        int flat = r * 256 + t;
        int o = flat >> 4, n2 = flat & 15;
        __builtin_nontemporal_store(otile[n2][o],
            &out[((size_t)b * COUT_ + o) * N_ + n0 + n2]);
    }
}

// ---------------------------------------------------------------------------
extern "C" void kernel_launch(void* const* d_in, const int* in_sizes, int n_in,
                              void* d_out, int out_size, void* d_ws, size_t ws_size,
                              hipStream_t stream) {
    const float* x    = (const float*)d_in[0];   // [B, C, N, 1]
    const int*   ei   = (const int*)  d_in[1];   // [2, B, N, K]
    const float* pos  = (const float*)d_in[2];   // [B, 3, N, 1]
    const float* W    = (const float*)d_in[3];   // [COUT, 2C]
    const float* bias = (const float*)d_in[4];   // [COUT]
    float*       out  = (float*)d_out;           // [B, COUT, N, 1]

    u16* xb    = (u16*)d_ws;                     // B*N*64 bf16 = 5.12 MB
    u16* wfrag = xb + (size_t)B_ * N_ * 64;      // 16 KB (B-frag layout)

    hipLaunchKernelGGL(precast, dim3(B_ * NBC + 1), dim3(256), 0, stream,
                       x, W, xb, wfrag);
    hipLaunchKernelGGL(fused, dim3(B_ * NB), dim3(256), 0, stream,
                       ei, pos, xb, wfrag, bias, out);
}